// Round 11
// baseline (928.443 us; speedup 1.0000x reference)
//
#include <hip/hip_runtime.h>
#include <math.h>

#define MUP 0.35f       // 1.4/sqrt(16)
#define SCALE 0.125f    // 1/sqrt(64)
#define EPS 1e-5f

typedef float f32x4 __attribute__((ext_vector_type(4)));

// workspace float offsets
#define WS_HA    0          // [4][1024] h at layer entry
#define WS_HB    4096       // [4][1024] h after attn residual input
#define WS_YMLP  8192       // [4][1024] atomic accum
#define WS_YO    12288      // [4][1024] atomic accum
#define WS_QKVP  16384      // [16][4][2048] qkv k-split partials
#define WS_OPART 278528     // [4][8][8][132] attn chunk partials
#define WS_GUP   413696     // [2][16][4][4096] gate/up k-split partials

// d_out float offsets
#define OUT_NK  4096
#define OUT_NV  (4096 + 16*4*8*2049*64)
#define OUT_SC  (4096 + 2*16*4*8*2049*64)

__device__ __forceinline__ float wsum64(float v) {
    v += __shfl_xor(v, 32); v += __shfl_xor(v, 16); v += __shfl_xor(v, 8);
    v += __shfl_xor(v, 4);  v += __shfl_xor(v, 2);  v += __shfl_xor(v, 1);
    return v;
}

__device__ __forceinline__ void fma4(float4& a, float s, const float4 w) {
    a.x = fmaf(s, w.x, a.x); a.y = fmaf(s, w.y, a.y);
    a.z = fmaf(s, w.z, a.z); a.w = fmaf(s, w.w, a.w);
}

__device__ __forceinline__ void nt_store4(const float4 v, float4* p) {
    f32x4 t = {v.x, v.y, v.z, v.w};
    __builtin_nontemporal_store(t, (f32x4*)p);
}

__global__ __launch_bounds__(256) void k_init(const float* __restrict__ emb,
                                              const int* __restrict__ cl,
                                              float* __restrict__ ws,
                                              float* __restrict__ out) {
    int tid = threadIdx.x;
    float4* ws4 = (float4*)ws;
    float4 z = {0.f, 0.f, 0.f, 0.f};
    if (blockIdx.x == 0) {
        const float4* e4 = (const float4*)emb;
        #pragma unroll
        for (int k = 0; k < 4; ++k) ws4[(WS_HA >> 2) + k * 256 + tid] = e4[k * 256 + tid];
        if (tid == 0) out[OUT_SC] = (float)(cl[0] + 1);
    } else if (blockIdx.x == 1) {
        #pragma unroll
        for (int k = 0; k < 4; ++k) ws4[(WS_YMLP >> 2) + k * 256 + tid] = z;
    } else {
        #pragma unroll
        for (int k = 0; k < 4; ++k) ws4[(WS_YO >> 2) + k * 256 + tid] = z;
    }
}

// ===== A: rms1 recompute + QKV GEMV (16 k-splits of 64 rows). grid 130, block 512 =====
__global__ __launch_bounds__(512) void k_a(const float* __restrict__ ln1,
                                           const float* __restrict__ wq,
                                           const float* __restrict__ wk,
                                           const float* __restrict__ wv,
                                           float* __restrict__ ws, int l) {
    float4* ws4 = (float4*)ws;
    const int tid = threadIdx.x, w = tid >> 6, lane = tid & 63;
    if (blockIdx.x >= 128) {            // zero YO (2 blocks x 512 float4)
        float4 z = {0,0,0,0};
        ws4[(WS_YO >> 2) + (blockIdx.x - 128) * 512 + tid] = z;
        return;
    }
    __shared__ float xs[4][64];
    __shared__ float4 red[8][64][4];
    __shared__ float sred[8][4];
    const int s = blockIdx.x >> 3, xt = blockIdx.x & 7;   // s: 0..15 k-split
    const int t2 = tid & 255;

    float4 hn[4]; float ss[4];
    #pragma unroll
    for (int b = 0; b < 4; ++b) {
        float4 h = ws4[(WS_HA >> 2) + b * 256 + t2];
        float4 y = ws4[(WS_YMLP >> 2) + b * 256 + t2];
        h.x = fmaf(MUP, y.x, h.x); h.y = fmaf(MUP, y.y, h.y);
        h.z = fmaf(MUP, y.z, h.z); h.w = fmaf(MUP, y.w, h.w);
        hn[b] = h;
        ss[b] = h.x*h.x + h.y*h.y + h.z*h.z + h.w*h.w;
    }
    #pragma unroll
    for (int b = 0; b < 4; ++b) {
        float v = wsum64(ss[b]);
        if (lane == 0) sred[w][b] = v;
    }
    __syncthreads();
    float rstd[4];
    #pragma unroll
    for (int b = 0; b < 4; ++b) {
        float tot = 0.f;
        #pragma unroll
        for (int ww = 0; ww < 8; ++ww) tot += sred[ww][b];
        rstd[b] = rsqrtf(tot * (1.f/2048.f) + EPS);   // 2x redundant sum
    }
    if (blockIdx.x == 0 && tid < 256) {
        #pragma unroll
        for (int b = 0; b < 4; ++b) ws4[(WS_HB >> 2) + b * 256 + t2] = hn[b];
    }
    {
        int tl = t2 - s * 16;
        if (tl >= 0 && tl < 16) {
            float4 g4 = ((const float4*)ln1)[l * 256 + t2];
            #pragma unroll
            for (int b = 0; b < 4; ++b) {
                float4 xv;
                xv.x = hn[b].x * rstd[b] * g4.x; xv.y = hn[b].y * rstd[b] * g4.y;
                xv.z = hn[b].z * rstd[b] * g4.z; xv.w = hn[b].w * rstd[b] * g4.w;
                ((float4*)xs[b])[tl] = xv;
            }
        }
    }
    __syncthreads();

    const float* Wp; int nc, c;
    if (xt < 4)      { Wp = wq + (size_t)l * 1024 * 1024; nc = 1024; c = xt * 256 + lane * 4; }
    else if (xt < 6) { Wp = wk + (size_t)l * 1024 * 512;  nc = 512;  c = (xt - 4) * 256 + lane * 4; }
    else             { Wp = wv + (size_t)l * 1024 * 512;  nc = 512;  c = (xt - 6) * 256 + lane * 4; }
    const float4* W4 = (const float4*)(Wp + c);
    const size_t nc4 = (size_t)(nc >> 2);
    float4 wr[8];
    #pragma unroll
    for (int i = 0; i < 8; ++i)
        wr[i] = W4[(size_t)(s * 64 + w * 8 + i) * nc4];
    float4 a0 = {0,0,0,0}, a1 = a0, a2 = a0, a3 = a0;
    #pragma unroll
    for (int i = 0; i < 8; ++i) {
        int r = w * 8 + i;
        fma4(a0, xs[0][r], wr[i]); fma4(a1, xs[1][r], wr[i]);
        fma4(a2, xs[2][r], wr[i]); fma4(a3, xs[3][r], wr[i]);
    }
    red[w][lane][0] = a0; red[w][lane][1] = a1;
    red[w][lane][2] = a2; red[w][lane][3] = a3;
    __syncthreads();
    if (w == 0) {
        float4* QKVP4 = ws4 + (WS_QKVP >> 2);
        #pragma unroll
        for (int b = 0; b < 4; ++b) {
            float4 sv = red[0][lane][b];
            #pragma unroll
            for (int ww = 1; ww < 8; ++ww) {
                float4 t = red[ww][lane][b];
                sv.x += t.x; sv.y += t.y; sv.z += t.z; sv.w += t.w;
            }
            QKVP4[(size_t)(s * 4 + b) * 512 + xt * 64 + lane] = sv;
        }
    }
}

// ===== B: single-pass flash-decode + fused cache copy, pipelined. grid 256, block 256 =====
__global__ __launch_bounds__(256) void k_b(const float* __restrict__ kc,
                                           const float* __restrict__ vc,
                                           const int* __restrict__ cl,
                                           float* __restrict__ ws,
                                           float* __restrict__ nk,
                                           float* __restrict__ nv, int l) {
    const int bid = blockIdx.x;
    const int b = bid >> 6, kvh = (bid >> 3) & 7, c = bid & 7;
    const int s0 = c * 256;
    const int tid = threadIdx.x, w = tid >> 6, lane = tid & 63;
    const int sub = lane >> 4, j = lane & 15;
    float4* ws4 = (float4*)ws;
    const float4* QKVP4 = (const float4*)ws4 + (WS_QKVP >> 2);

    __shared__ float4 oac[2][16][16];   // [head][group][j]
    __shared__ float mlm[2][16], mll[2][16];

    const float pos = (float)cl[0];
    float cs4[4], sn4[4];
    #pragma unroll
    for (int m = 0; m < 4; ++m) {
        float t = (float)(4 * (j & 7) + m);
        float fr = pos * __expf(-t * 0.2878231366242557f);  // ln(1e4)/32
        cs4[m] = cosf(fr); sn4[m] = sinf(fr);
    }
    const float sgn = (j < 8) ? -1.f : 1.f;

    // q reduce over 16 k-split partials + RoPE
    float4 q0 = {0,0,0,0}, q1 = {0,0,0,0};
    #pragma unroll
    for (int sp = 0; sp < 16; ++sp) {
        const float4* qp = QKVP4 + (size_t)(sp * 4 + b) * 512 + kvh * 32;
        float4 t0 = qp[j], t1 = qp[16 + j];
        q0.x += t0.x; q0.y += t0.y; q0.z += t0.z; q0.w += t0.w;
        q1.x += t1.x; q1.y += t1.y; q1.z += t1.z; q1.w += t1.w;
    }
    {
        float4 q0p, q1p;
        q0p.x = __shfl_xor(q0.x, 8); q0p.y = __shfl_xor(q0.y, 8);
        q0p.z = __shfl_xor(q0.z, 8); q0p.w = __shfl_xor(q0.w, 8);
        q1p.x = __shfl_xor(q1.x, 8); q1p.y = __shfl_xor(q1.y, 8);
        q1p.z = __shfl_xor(q1.z, 8); q1p.w = __shfl_xor(q1.w, 8);
        q0.x = q0.x * cs4[0] + sgn * q0p.x * sn4[0];
        q0.y = q0.y * cs4[1] + sgn * q0p.y * sn4[1];
        q0.z = q0.z * cs4[2] + sgn * q0p.z * sn4[2];
        q0.w = q0.w * cs4[3] + sgn * q0p.w * sn4[3];
        q1.x = q1.x * cs4[0] + sgn * q1p.x * sn4[0];
        q1.y = q1.y * cs4[1] + sgn * q1p.y * sn4[1];
        q1.z = q1.z * cs4[2] + sgn * q1p.z * sn4[2];
        q1.w = q1.w * cs4[3] + sgn * q1p.w * sn4[3];
    }

    const size_t cbase = (size_t)((l * 4 + b) * 8 + kvh);
    const float4* kc4 = (const float4*)kc + cbase * 2048 * 16;
    const float4* vc4 = (const float4*)vc + cbase * 2048 * 16;
    float4* nk4 = (float4*)nk + cbase * 2049 * 16;
    float4* nv4 = (float4*)nv + cbase * 2049 * 16;

    float m0 = -1e30f, m1 = -1e30f, l0 = 0.f, l1 = 0.f;
    float4 o0 = {0,0,0,0}, o1 = {0,0,0,0};
    float4 kr[2][4], vr[2][4];

    // prologue: load group 0
    #pragma unroll
    for (int ii = 0; ii < 4; ++ii) {
        int r = s0 + w * 16 + ii * 4 + sub;
        kr[0][ii] = kc4[(size_t)r * 16 + j];
        vr[0][ii] = vc4[(size_t)r * 16 + j];
    }
    #pragma unroll
    for (int g = 0; g < 4; ++g) {
        const int cur = g & 1, nxt = cur ^ 1;
        const int rb = s0 + g * 64 + w * 16;
        if (g < 3) {
            const int rn = s0 + (g + 1) * 64 + w * 16;
            #pragma unroll
            for (int ii = 0; ii < 4; ++ii) {
                int r = rn + ii * 4 + sub;
                kr[nxt][ii] = kc4[(size_t)r * 16 + j];
                vr[nxt][ii] = vc4[(size_t)r * 16 + j];
            }
        }
        #pragma unroll
        for (int ii = 0; ii < 4; ++ii) {
            int r = rb + ii * 4 + sub;
            nt_store4(kr[cur][ii], &nk4[(size_t)r * 16 + j]);
            nt_store4(vr[cur][ii], &nv4[(size_t)r * 16 + j]);
        }
        #pragma unroll
        for (int ii = 0; ii < 4; ++ii) {
            float4 kv = kr[cur][ii];
            float d0 = kv.x*q0.x + kv.y*q0.y + kv.z*q0.z + kv.w*q0.w;
            float d1 = kv.x*q1.x + kv.y*q1.y + kv.z*q1.z + kv.w*q1.w;
            d0 += __shfl_xor(d0, 1); d0 += __shfl_xor(d0, 2);
            d0 += __shfl_xor(d0, 4); d0 += __shfl_xor(d0, 8);
            d1 += __shfl_xor(d1, 1); d1 += __shfl_xor(d1, 2);
            d1 += __shfl_xor(d1, 4); d1 += __shfl_xor(d1, 8);
            d0 *= SCALE; d1 *= SCALE;
            float mn0 = fmaxf(m0, d0);
            float e0 = __expf(m0 - mn0), p0 = __expf(d0 - mn0);
            o0.x = o0.x*e0 + p0*vr[cur][ii].x; o0.y = o0.y*e0 + p0*vr[cur][ii].y;
            o0.z = o0.z*e0 + p0*vr[cur][ii].z; o0.w = o0.w*e0 + p0*vr[cur][ii].w;
            l0 = l0*e0 + p0; m0 = mn0;
            float mn1 = fmaxf(m1, d1);
            float e1 = __expf(m1 - mn1), p1 = __expf(d1 - mn1);
            o1.x = o1.x*e1 + p1*vr[cur][ii].x; o1.y = o1.y*e1 + p1*vr[cur][ii].y;
            o1.z = o1.z*e1 + p1*vr[cur][ii].z; o1.w = o1.w*e1 + p1*vr[cur][ii].w;
            l1 = l1*e1 + p1; m1 = mn1;
        }
    }
    if (c == 7 && w == 0 && sub == 0) {
        float4 kv = {0,0,0,0}, vnew = {0,0,0,0};
        #pragma unroll
        for (int sp = 0; sp < 16; ++sp) {
            const float4* pp = QKVP4 + (size_t)(sp * 4 + b) * 512;
            float4 t0 = pp[256 + kvh * 16 + j];
            float4 t1 = pp[384 + kvh * 16 + j];
            kv.x += t0.x; kv.y += t0.y; kv.z += t0.z; kv.w += t0.w;
            vnew.x += t1.x; vnew.y += t1.y; vnew.z += t1.z; vnew.w += t1.w;
        }
        float4 kp;
        kp.x = __shfl_xor(kv.x, 8); kp.y = __shfl_xor(kv.y, 8);
        kp.z = __shfl_xor(kv.z, 8); kp.w = __shfl_xor(kv.w, 8);
        kv.x = kv.x * cs4[0] + sgn * kp.x * sn4[0];
        kv.y = kv.y * cs4[1] + sgn * kp.y * sn4[1];
        kv.z = kv.z * cs4[2] + sgn * kp.z * sn4[2];
        kv.w = kv.w * cs4[3] + sgn * kp.w * sn4[3];
        nk4[(size_t)2048 * 16 + j] = kv;
        nv4[(size_t)2048 * 16 + j] = vnew;
        float d0 = kv.x*q0.x + kv.y*q0.y + kv.z*q0.z + kv.w*q0.w;
        float d1 = kv.x*q1.x + kv.y*q1.y + kv.z*q1.z + kv.w*q1.w;
        d0 += __shfl_xor(d0, 1); d0 += __shfl_xor(d0, 2);
        d0 += __shfl_xor(d0, 4); d0 += __shfl_xor(d0, 8);
        d1 += __shfl_xor(d1, 1); d1 += __shfl_xor(d1, 2);
        d1 += __shfl_xor(d1, 4); d1 += __shfl_xor(d1, 8);
        d0 *= SCALE; d1 *= SCALE;
        float mn0 = fmaxf(m0, d0);
        float e0 = __expf(m0 - mn0), p0 = __expf(d0 - mn0);
        o0.x = o0.x*e0 + p0*vnew.x; o0.y = o0.y*e0 + p0*vnew.y;
        o0.z = o0.z*e0 + p0*vnew.z; o0.w = o0.w*e0 + p0*vnew.w;
        l0 = l0*e0 + p0; m0 = mn0;
        float mn1 = fmaxf(m1, d1);
        float e1 = __expf(m1 - mn1), p1 = __expf(d1 - mn1);
        o1.x = o1.x*e1 + p1*vnew.x; o1.y = o1.y*e1 + p1*vnew.y;
        o1.z = o1.z*e1 + p1*vnew.z; o1.w = o1.w*e1 + p1*vnew.w;
        l1 = l1*e1 + p1; m1 = mn1;
    }
    const int grp = w * 4 + sub;
    oac[0][grp][j] = o0;
    oac[1][grp][j] = o1;
    if (j == 0) {
        mlm[0][grp] = m0; mll[0][grp] = l0;
        mlm[1][grp] = m1; mll[1][grp] = l1;
    }
    __syncthreads();
    if (tid < 128) {
        const int h = tid >> 6, d = tid & 63;
        const float* oa = (const float*)&oac[h][0][0];   // [16][64]
        float M = -1e30f;
        #pragma unroll
        for (int g2 = 0; g2 < 16; ++g2) M = fmaxf(M, mlm[h][g2]);
        float ot = 0.f, lt = 0.f;
        #pragma unroll
        for (int g2 = 0; g2 < 16; ++g2) {
            float e = __expf(mlm[h][g2] - M);
            ot += oa[g2 * 64 + d] * e;
            lt += mll[h][g2] * e;
        }
        int pbase = WS_OPART + ((b * 8 + kvh) * 8 + c) * 132;
        ws[pbase + h * 64 + d] = ot;
        if (d == 0) { ws[pbase + 128 + 2 * h] = M; ws[pbase + 129 + 2 * h] = lt; }
    }
}

// ===== C: chunk-combine (8) + O-proj GEMV (16 k-splits of 64 rows). grid 66, block 512 =====
__global__ __launch_bounds__(512) void k_c(const float* __restrict__ wo,
                                           float* __restrict__ ws, int l) {
    float4* ws4 = (float4*)ws;
    const int tid = threadIdx.x, w = tid >> 6, lane = tid & 63;
    if (blockIdx.x >= 64) {             // zero YMLP
        float4 z = {0,0,0,0};
        ws4[(WS_YMLP >> 2) + (blockIdx.x - 64) * 512 + tid] = z;
        return;
    }
    __shared__ float xs[4][64];
    __shared__ float4 red[8][64][4];
    const int xt = blockIdx.x & 3, s = blockIdx.x >> 2;   // s: 0..15
    if (tid < 256) {
        const int bb = tid >> 6, rr = tid & 63;
        const int r = s * 64 + rr;
        const int kvh = r >> 7, g = (r >> 6) & 1, d = r & 63;
        const float* bp = ws + WS_OPART + (size_t)((bb * 8 + kvh) * 8) * 132;
        float m = -1e30f;
        #pragma unroll
        for (int cc = 0; cc < 8; ++cc)
            m = fmaxf(m, bp[cc * 132 + 128 + 2 * g]);
        float lt = 0.f, ot = 0.f;
        #pragma unroll
        for (int cc = 0; cc < 8; ++cc) {
            float f = __expf(bp[cc * 132 + 128 + 2 * g] - m);
            lt += bp[cc * 132 + 129 + 2 * g] * f;
            ot += bp[cc * 132 + g * 64 + d] * f;
        }
        xs[bb][rr] = ot / lt;
    }
    __syncthreads();
    const float4* W4 = (const float4*)(wo + (size_t)l * 1024 * 1024 + xt * 256 + lane * 4);
    float4 wr[8];
    #pragma unroll
    for (int i = 0; i < 8; ++i)
        wr[i] = W4[(size_t)(s * 64 + w * 8 + i) * 256];
    float4 a0 = {0,0,0,0}, a1 = a0, a2 = a0, a3 = a0;
    #pragma unroll
    for (int i = 0; i < 8; ++i) {
        int r = w * 8 + i;
        fma4(a0, xs[0][r], wr[i]); fma4(a1, xs[1][r], wr[i]);
        fma4(a2, xs[2][r], wr[i]); fma4(a3, xs[3][r], wr[i]);
    }
    red[w][lane][0] = a0; red[w][lane][1] = a1;
    red[w][lane][2] = a2; red[w][lane][3] = a3;
    __syncthreads();
    if (w == 0) {
        int c = xt * 256 + lane * 4;
        #pragma unroll
        for (int b = 0; b < 4; ++b) {
            float4 sv = red[0][lane][b];
            #pragma unroll
            for (int ww = 1; ww < 8; ++ww) {
                float4 t = red[ww][lane][b];
                sv.x += t.x; sv.y += t.y; sv.z += t.z; sv.w += t.w;
            }
            atomicAdd(&ws[WS_YO + b * 1024 + c + 0], sv.x);
            atomicAdd(&ws[WS_YO + b * 1024 + c + 1], sv.y);
            atomicAdd(&ws[WS_YO + b * 1024 + c + 2], sv.z);
            atomicAdd(&ws[WS_YO + b * 1024 + c + 3], sv.w);
        }
    }
}

// ===== D: rms2 recompute + gate AND up GEMV (16 k-splits of 64 rows). grid (16,16), block 512 =====
__global__ __launch_bounds__(512) void k_d(const float* __restrict__ ln2,
                                           const float* __restrict__ wg,
                                           const float* __restrict__ wu,
                                           float* __restrict__ ws, int l) {
    float4* ws4 = (float4*)ws;
    const int tid = threadIdx.x, w = tid >> 6, lane = tid & 63;
    __shared__ float xs[4][64];
    __shared__ float4 red[8][64][4];
    __shared__ float sred[8][4];
    const int t16 = blockIdx.x, y = blockIdx.y;   // y: 0..15 k-split
    const int t2 = tid & 255;

    float4 hn[4]; float ss[4];
    #pragma unroll
    for (int b = 0; b < 4; ++b) {
        float4 h = ws4[(WS_HB >> 2) + b * 256 + t2];
        float4 yv = ws4[(WS_YO >> 2) + b * 256 + t2];
        h.x = fmaf(MUP, yv.x, h.x); h.y = fmaf(MUP, yv.y, h.y);
        h.z = fmaf(MUP, yv.z, h.z); h.w = fmaf(MUP, yv.w, h.w);
        hn[b] = h;
        ss[b] = h.x*h.x + h.y*h.y + h.z*h.z + h.w*h.w;
    }
    #pragma unroll
    for (int b = 0; b < 4; ++b) {
        float v = wsum64(ss[b]);
        if (lane == 0) sred[w][b] = v;
    }
    __syncthreads();
    float rstd[4];
    #pragma unroll
    for (int b = 0; b < 4; ++b) {
        float tot = 0.f;
        #pragma unroll
        for (int ww = 0; ww < 8; ++ww) tot += sred[ww][b];
        rstd[b] = rsqrtf(tot * (1.f/2048.f) + EPS);
    }
    if (blockIdx.x == 0 && blockIdx.y == 0 && tid < 256) {
        #pragma unroll
        for (int b = 0; b < 4; ++b) ws4[(WS_HA >> 2) + b * 256 + t2] = hn[b];
    }
    {
        int tl = t2 - y * 16;
        if (tl >= 0 && tl < 16) {
            float4 g4 = ((const float4*)ln2)[l * 256 + t2];
            #pragma unroll
            for (int b = 0; b < 4; ++b) {
                float4 xv;
                xv.x = hn[b].x * rstd[b] * g4.x; xv.y = hn[b].y * rstd[b] * g4.y;
                xv.z = hn[b].z * rstd[b] * g4.z; xv.w = hn[b].w * rstd[b] * g4.w;
                ((float4*)xs[b])[tl] = xv;
            }
        }
    }
    __syncthreads();
    float4* GUP4 = ws4 + (WS_GUP >> 2);

    #pragma unroll
    for (int mat = 0; mat < 2; ++mat) {
        const float* Wm = (mat ? wu : wg) + (size_t)l * 1024 * 4096;
        const float4* W4 = (const float4*)(Wm + t16 * 256 + lane * 4);
        float4 wr[8];
        #pragma unroll
        for (int i = 0; i < 8; ++i)
            wr[i] = W4[(size_t)(y * 64 + w * 8 + i) * 1024];
        float4 a0 = {0,0,0,0}, a1 = a0, a2 = a0, a3 = a0;
        #pragma unroll
        for (int i = 0; i < 8; ++i) {
            int r = w * 8 + i;
            fma4(a0, xs[0][r], wr[i]); fma4(a1, xs[1][r], wr[i]);
            fma4(a2, xs[2][r], wr[i]); fma4(a3, xs[3][r], wr[i]);
        }
        red[w][lane][0] = a0; red[w][lane][1] = a1;
        red[w][lane][2] = a2; red[w][lane][3] = a3;
        __syncthreads();
        if (w == 0) {
            #pragma unroll
            for (int b = 0; b < 4; ++b) {
                float4 sv = red[0][lane][b];
                #pragma unroll
                for (int ww = 1; ww < 8; ++ww) {
                    float4 t = red[ww][lane][b];
                    sv.x += t.x; sv.y += t.y; sv.z += t.z; sv.w += t.w;
                }
                GUP4[(size_t)((mat * 16 + y) * 4 + b) * 1024 + t16 * 64 + lane] = sv;
            }
        }
        __syncthreads();
    }
}

// ===== E: silu-combine + down GEMV (64 f-splits of 64 rows). grid (4,64), block 512 =====
__global__ __launch_bounds__(512) void k_e(const float* __restrict__ wd,
                                           float* __restrict__ ws, int l) {
    float4* ws4 = (float4*)ws;
    const int tid = threadIdx.x, w = tid >> 6, lane = tid & 63;
    __shared__ float ts[4][64];
    __shared__ float4 red[8][64][4];
    const int xt = blockIdx.x, s = blockIdx.y;   // s: 0..63
    if (tid < 64) {
        const int bb = tid >> 4, i = tid & 15;
        const int f4 = s * 16 + i;
        const float4* GUP4 = (const float4*)ws4 + (WS_GUP >> 2);
        float4 g = {0,0,0,0}, u = {0,0,0,0};
        #pragma unroll
        for (int sp = 0; sp < 16; ++sp) {
            float4 gv = GUP4[(size_t)(sp * 4 + bb) * 1024 + f4];
            float4 uv = GUP4[(size_t)((16 + sp) * 4 + bb) * 1024 + f4];
            g.x += gv.x; g.y += gv.y; g.z += gv.z; g.w += gv.w;
            u.x += uv.x; u.y += uv.y; u.z += uv.z; u.w += uv.w;
        }
        float4 t;
        t.x = (g.x / (1.f + __expf(-g.x))) * u.x;
        t.y = (g.y / (1.f + __expf(-g.y))) * u.y;
        t.z = (g.z / (1.f + __expf(-g.z))) * u.z;
        t.w = (g.w / (1.f + __expf(-g.w))) * u.w;
        ((float4*)ts[bb])[i] = t;
    }
    __syncthreads();
    const float4* W4 = (const float4*)(wd + (size_t)l * 4096 * 1024 + xt * 256 + lane * 4);
    float4 wr[8];
    #pragma unroll
    for (int i = 0; i < 8; ++i)
        wr[i] = W4[(size_t)(s * 64 + w * 8 + i) * 256];
    float4 a0 = {0,0,0,0}, a1 = a0, a2 = a0, a3 = a0;
    #pragma unroll
    for (int i = 0; i < 8; ++i) {
        int r = w * 8 + i;
        fma4(a0, ts[0][r], wr[i]); fma4(a1, ts[1][r], wr[i]);
        fma4(a2, ts[2][r], wr[i]); fma4(a3, ts[3][r], wr[i]);
    }
    red[w][lane][0] = a0; red[w][lane][1] = a1;
    red[w][lane][2] = a2; red[w][lane][3] = a3;
    __syncthreads();
    if (w == 0) {
        int c = xt * 256 + lane * 4;
        #pragma unroll
        for (int b = 0; b < 4; ++b) {
            float4 sv = red[0][lane][b];
            #pragma unroll
            for (int ww = 1; ww < 8; ++ww) {
                float4 t = red[ww][lane][b];
                sv.x += t.x; sv.y += t.y; sv.z += t.z; sv.w += t.w;
            }
            atomicAdd(&ws[WS_YMLP + b * 1024 + c + 0], sv.x);
            atomicAdd(&ws[WS_YMLP + b * 1024 + c + 1], sv.y);
            atomicAdd(&ws[WS_YMLP + b * 1024 + c + 2], sv.z);
            atomicAdd(&ws[WS_YMLP + b * 1024 + c + 3], sv.w);
        }
    }
}

__global__ __launch_bounds__(256) void k_final(const float* __restrict__ normw,
                                               float* __restrict__ ws,
                                               float* __restrict__ out) {
    float4* ws4 = (float4*)ws;
    int tid = threadIdx.x;
    int b = blockIdx.x, w = tid >> 6, lane = tid & 63;
    __shared__ float sred[4];
    float4 h = ws4[(WS_HA >> 2) + b * 256 + tid];
    float4 y = ws4[(WS_YMLP >> 2) + b * 256 + tid];
    h.x = fmaf(MUP, y.x, h.x); h.y = fmaf(MUP, y.y, h.y);
    h.z = fmaf(MUP, y.z, h.z); h.w = fmaf(MUP, y.w, h.w);
    float ssv = h.x*h.x + h.y*h.y + h.z*h.z + h.w*h.w;
    float v = wsum64(ssv);
    if (lane == 0) sred[w] = v;
    __syncthreads();
    float rstd = rsqrtf((sred[0] + sred[1] + sred[2] + sred[3]) * (1.f/1024.f) + EPS);
    float4 g4 = ((const float4*)normw)[tid];
    float4 o;
    o.x = h.x * rstd * g4.x; o.y = h.y * rstd * g4.y;
    o.z = h.z * rstd * g4.z; o.w = h.w * rstd * g4.w;
    ((float4*)out)[b * 256 + tid] = o;
}

extern "C" void kernel_launch(void* const* d_in, const int* in_sizes, int n_in,
                              void* d_out, int out_size, void* d_ws, size_t ws_size,
                              hipStream_t stream) {
    const float* emb  = (const float*)d_in[0];
    const float* kc   = (const float*)d_in[1];
    const float* vc   = (const float*)d_in[2];
    const float* ln1  = (const float*)d_in[3];
    const float* ln2  = (const float*)d_in[4];
    const float* nrmw = (const float*)d_in[5];
    const float* wq   = (const float*)d_in[6];
    const float* wk   = (const float*)d_in[7];
    const float* wv   = (const float*)d_in[8];
    const float* wo   = (const float*)d_in[9];
    const float* wg   = (const float*)d_in[10];
    const float* wu   = (const float*)d_in[11];
    const float* wd   = (const float*)d_in[12];
    const int*   cl   = (const int*)d_in[13];

    float* out = (float*)d_out;
    float* ws  = (float*)d_ws;
    float* nk  = out + OUT_NK;
    float* nv  = out + OUT_NV;

    k_init<<<3, 256, 0, stream>>>(emb, cl, ws, out);
    for (int l = 0; l < 16; ++l) {
        k_a<<<130, 512, 0, stream>>>(ln1, wq, wk, wv, ws, l);
        k_b<<<256, 256, 0, stream>>>(kc, vc, cl, ws, nk, nv, l);
        k_c<<<66, 512, 0, stream>>>(wo, ws, l);
        k_d<<<dim3(16, 16), 512, 0, stream>>>(ln2, wg, wu, ws, l);
        k_e<<<dim3(4, 64), 512, 0, stream>>>(wd, ws, l);
    }
    k_final<<<4, 256, 0, stream>>>(nrmw, ws, out);
}

// Round 12
// 898.801 us; speedup vs baseline: 1.0330x; 1.0330x over previous
//
#include <hip/hip_runtime.h>
#include <math.h>

#define MUP 0.35f       // 1.4/sqrt(16)
#define SCALE 0.125f    // 1/sqrt(64)
#define EPS 1e-5f

typedef float f32x4 __attribute__((ext_vector_type(4)));

// workspace float offsets
#define WS_HA    0          // [4][1024] h at layer entry
#define WS_HB    4096       // [4][1024] h after attn residual input
#define WS_YMLP  8192       // [4][1024] atomic accum
#define WS_YO    12288      // [4][1024] atomic accum
#define WS_QKVP  16384      // [8][4][2048] qkv k-split partials
#define WS_OPART 278528     // [4][8][8][132] attn chunk partials
#define WS_GUP   413696     // [2][16][4][4096] gate/up k-split partials

// d_out float offsets
#define OUT_NK  4096
#define OUT_NV  (4096 + 16*4*8*2049*64)
#define OUT_SC  (4096 + 2*16*4*8*2049*64)

__device__ __forceinline__ float wsum64(float v) {
    v += __shfl_xor(v, 32); v += __shfl_xor(v, 16); v += __shfl_xor(v, 8);
    v += __shfl_xor(v, 4);  v += __shfl_xor(v, 2);  v += __shfl_xor(v, 1);
    return v;
}

__device__ __forceinline__ void fma4(float4& a, float s, const float4 w) {
    a.x = fmaf(s, w.x, a.x); a.y = fmaf(s, w.y, a.y);
    a.z = fmaf(s, w.z, a.z); a.w = fmaf(s, w.w, a.w);
}

__device__ __forceinline__ void nt_store4(const float4 v, float4* p) {
    f32x4 t = {v.x, v.y, v.z, v.w};
    __builtin_nontemporal_store(t, (f32x4*)p);
}

__global__ __launch_bounds__(256) void k_init(const float* __restrict__ emb,
                                              const int* __restrict__ cl,
                                              float* __restrict__ ws,
                                              float* __restrict__ out) {
    int tid = threadIdx.x;
    float4* ws4 = (float4*)ws;
    float4 z = {0.f, 0.f, 0.f, 0.f};
    if (blockIdx.x == 0) {
        const float4* e4 = (const float4*)emb;
        #pragma unroll
        for (int k = 0; k < 4; ++k) ws4[(WS_HA >> 2) + k * 256 + tid] = e4[k * 256 + tid];
        if (tid == 0) out[OUT_SC] = (float)(cl[0] + 1);
    } else if (blockIdx.x == 1) {
        #pragma unroll
        for (int k = 0; k < 4; ++k) ws4[(WS_YMLP >> 2) + k * 256 + tid] = z;
    } else {
        #pragma unroll
        for (int k = 0; k < 4; ++k) ws4[(WS_YO >> 2) + k * 256 + tid] = z;
    }
}

// ===== A: rms1 recompute + QKV GEMV (8 k-splits of 128 rows). grid 66, block 512 =====
__global__ __launch_bounds__(512) void k_a(const float* __restrict__ ln1,
                                           const float* __restrict__ wq,
                                           const float* __restrict__ wk,
                                           const float* __restrict__ wv,
                                           float* __restrict__ ws, int l) {
    float4* ws4 = (float4*)ws;
    const int tid = threadIdx.x, w = tid >> 6, lane = tid & 63;
    if (blockIdx.x >= 64) {             // zero YO (2 blocks x 512 float4)
        float4 z = {0,0,0,0};
        ws4[(WS_YO >> 2) + (blockIdx.x - 64) * 512 + tid] = z;
        return;
    }
    __shared__ float xs[4][128];
    __shared__ float4 red[8][64][4];
    __shared__ float sred[8][4];
    const int s = blockIdx.x >> 3, xt = blockIdx.x & 7;   // s: 0..7 k-split
    const int t2 = tid & 255;

    float4 hn[4]; float ss[4];
    #pragma unroll
    for (int b = 0; b < 4; ++b) {
        float4 h = ws4[(WS_HA >> 2) + b * 256 + t2];
        float4 y = ws4[(WS_YMLP >> 2) + b * 256 + t2];
        h.x = fmaf(MUP, y.x, h.x); h.y = fmaf(MUP, y.y, h.y);
        h.z = fmaf(MUP, y.z, h.z); h.w = fmaf(MUP, y.w, h.w);
        hn[b] = h;
        ss[b] = h.x*h.x + h.y*h.y + h.z*h.z + h.w*h.w;
    }
    #pragma unroll
    for (int b = 0; b < 4; ++b) {
        float v = wsum64(ss[b]);
        if (lane == 0) sred[w][b] = v;
    }
    __syncthreads();
    float rstd[4];
    #pragma unroll
    for (int b = 0; b < 4; ++b) {
        float tot = 0.f;
        #pragma unroll
        for (int ww = 0; ww < 8; ++ww) tot += sred[ww][b];
        rstd[b] = rsqrtf(tot * (1.f/2048.f) + EPS);   // 2x redundant sum
    }
    if (blockIdx.x == 0 && tid < 256) {
        #pragma unroll
        for (int b = 0; b < 4; ++b) ws4[(WS_HB >> 2) + b * 256 + t2] = hn[b];
    }
    {
        int tl = t2 - s * 32;
        if (tl >= 0 && tl < 32) {
            float4 g4 = ((const float4*)ln1)[l * 256 + t2];
            #pragma unroll
            for (int b = 0; b < 4; ++b) {
                float4 xv;
                xv.x = hn[b].x * rstd[b] * g4.x; xv.y = hn[b].y * rstd[b] * g4.y;
                xv.z = hn[b].z * rstd[b] * g4.z; xv.w = hn[b].w * rstd[b] * g4.w;
                ((float4*)xs[b])[tl] = xv;
            }
        }
    }
    __syncthreads();

    const float* Wp; int nc, c;
    if (xt < 4)      { Wp = wq + (size_t)l * 1024 * 1024; nc = 1024; c = xt * 256 + lane * 4; }
    else if (xt < 6) { Wp = wk + (size_t)l * 1024 * 512;  nc = 512;  c = (xt - 4) * 256 + lane * 4; }
    else             { Wp = wv + (size_t)l * 1024 * 512;  nc = 512;  c = (xt - 6) * 256 + lane * 4; }
    const float4* W4 = (const float4*)(Wp + c);
    const size_t nc4 = (size_t)(nc >> 2);
    float4 a0 = {0,0,0,0}, a1 = a0, a2 = a0, a3 = a0;
    #pragma unroll
    for (int ch = 0; ch < 2; ++ch) {
        float4 wr[8];
        #pragma unroll
        for (int i = 0; i < 8; ++i)
            wr[i] = W4[(size_t)(s * 128 + w * 16 + ch * 8 + i) * nc4];
        #pragma unroll
        for (int i = 0; i < 8; ++i) {
            int r = w * 16 + ch * 8 + i;
            fma4(a0, xs[0][r], wr[i]); fma4(a1, xs[1][r], wr[i]);
            fma4(a2, xs[2][r], wr[i]); fma4(a3, xs[3][r], wr[i]);
        }
    }
    red[w][lane][0] = a0; red[w][lane][1] = a1;
    red[w][lane][2] = a2; red[w][lane][3] = a3;
    __syncthreads();
    if (w == 0) {
        float4* QKVP4 = ws4 + (WS_QKVP >> 2);
        #pragma unroll
        for (int b = 0; b < 4; ++b) {
            float4 sv = red[0][lane][b];
            #pragma unroll
            for (int ww = 1; ww < 8; ++ww) {
                float4 t = red[ww][lane][b];
                sv.x += t.x; sv.y += t.y; sv.z += t.z; sv.w += t.w;
            }
            QKVP4[(size_t)(s * 4 + b) * 512 + xt * 64 + lane] = sv;
        }
    }
}

// ===== B: single-pass flash-decode + fused cache copy, pipelined. grid 256, block 256 =====
__global__ __launch_bounds__(256) void k_b(const float* __restrict__ kc,
                                           const float* __restrict__ vc,
                                           const int* __restrict__ cl,
                                           float* __restrict__ ws,
                                           float* __restrict__ nk,
                                           float* __restrict__ nv, int l) {
    const int bid = blockIdx.x;
    const int b = bid >> 6, kvh = (bid >> 3) & 7, c = bid & 7;
    const int s0 = c * 256;
    const int tid = threadIdx.x, w = tid >> 6, lane = tid & 63;
    const int sub = lane >> 4, j = lane & 15;
    float4* ws4 = (float4*)ws;
    const float4* QKVP4 = (const float4*)ws4 + (WS_QKVP >> 2);

    __shared__ float4 oac[2][16][16];   // [head][group][j]
    __shared__ float mlm[2][16], mll[2][16];

    const float pos = (float)cl[0];
    float cs4[4], sn4[4];
    #pragma unroll
    for (int m = 0; m < 4; ++m) {
        float t = (float)(4 * (j & 7) + m);
        float fr = pos * __expf(-t * 0.2878231366242557f);  // ln(1e4)/32
        cs4[m] = cosf(fr); sn4[m] = sinf(fr);
    }
    const float sgn = (j < 8) ? -1.f : 1.f;

    // q reduce over 8 k-split partials + RoPE
    float4 q0 = {0,0,0,0}, q1 = {0,0,0,0};
    #pragma unroll
    for (int sp = 0; sp < 8; ++sp) {
        const float4* qp = QKVP4 + (size_t)(sp * 4 + b) * 512 + kvh * 32;
        float4 t0 = qp[j], t1 = qp[16 + j];
        q0.x += t0.x; q0.y += t0.y; q0.z += t0.z; q0.w += t0.w;
        q1.x += t1.x; q1.y += t1.y; q1.z += t1.z; q1.w += t1.w;
    }
    {
        float4 q0p, q1p;
        q0p.x = __shfl_xor(q0.x, 8); q0p.y = __shfl_xor(q0.y, 8);
        q0p.z = __shfl_xor(q0.z, 8); q0p.w = __shfl_xor(q0.w, 8);
        q1p.x = __shfl_xor(q1.x, 8); q1p.y = __shfl_xor(q1.y, 8);
        q1p.z = __shfl_xor(q1.z, 8); q1p.w = __shfl_xor(q1.w, 8);
        q0.x = q0.x * cs4[0] + sgn * q0p.x * sn4[0];
        q0.y = q0.y * cs4[1] + sgn * q0p.y * sn4[1];
        q0.z = q0.z * cs4[2] + sgn * q0p.z * sn4[2];
        q0.w = q0.w * cs4[3] + sgn * q0p.w * sn4[3];
        q1.x = q1.x * cs4[0] + sgn * q1p.x * sn4[0];
        q1.y = q1.y * cs4[1] + sgn * q1p.y * sn4[1];
        q1.z = q1.z * cs4[2] + sgn * q1p.z * sn4[2];
        q1.w = q1.w * cs4[3] + sgn * q1p.w * sn4[3];
    }

    const size_t cbase = (size_t)((l * 4 + b) * 8 + kvh);
    const float4* kc4 = (const float4*)kc + cbase * 2048 * 16;
    const float4* vc4 = (const float4*)vc + cbase * 2048 * 16;
    float4* nk4 = (float4*)nk + cbase * 2049 * 16;
    float4* nv4 = (float4*)nv + cbase * 2049 * 16;

    float m0 = -1e30f, m1 = -1e30f, l0 = 0.f, l1 = 0.f;
    float4 o0 = {0,0,0,0}, o1 = {0,0,0,0};
    float4 kr[2][4], vr[2][4];

    // prologue: load group 0
    #pragma unroll
    for (int ii = 0; ii < 4; ++ii) {
        int r = s0 + w * 16 + ii * 4 + sub;
        kr[0][ii] = kc4[(size_t)r * 16 + j];
        vr[0][ii] = vc4[(size_t)r * 16 + j];
    }
    #pragma unroll
    for (int g = 0; g < 4; ++g) {
        const int cur = g & 1, nxt = cur ^ 1;
        const int rb = s0 + g * 64 + w * 16;
        if (g < 3) {
            const int rn = s0 + (g + 1) * 64 + w * 16;
            #pragma unroll
            for (int ii = 0; ii < 4; ++ii) {
                int r = rn + ii * 4 + sub;
                kr[nxt][ii] = kc4[(size_t)r * 16 + j];
                vr[nxt][ii] = vc4[(size_t)r * 16 + j];
            }
        }
        #pragma unroll
        for (int ii = 0; ii < 4; ++ii) {
            int r = rb + ii * 4 + sub;
            nt_store4(kr[cur][ii], &nk4[(size_t)r * 16 + j]);
            nt_store4(vr[cur][ii], &nv4[(size_t)r * 16 + j]);
        }
        #pragma unroll
        for (int ii = 0; ii < 4; ++ii) {
            float4 kv = kr[cur][ii];
            float d0 = kv.x*q0.x + kv.y*q0.y + kv.z*q0.z + kv.w*q0.w;
            float d1 = kv.x*q1.x + kv.y*q1.y + kv.z*q1.z + kv.w*q1.w;
            d0 += __shfl_xor(d0, 1); d0 += __shfl_xor(d0, 2);
            d0 += __shfl_xor(d0, 4); d0 += __shfl_xor(d0, 8);
            d1 += __shfl_xor(d1, 1); d1 += __shfl_xor(d1, 2);
            d1 += __shfl_xor(d1, 4); d1 += __shfl_xor(d1, 8);
            d0 *= SCALE; d1 *= SCALE;
            float mn0 = fmaxf(m0, d0);
            float e0 = __expf(m0 - mn0), p0 = __expf(d0 - mn0);
            o0.x = o0.x*e0 + p0*vr[cur][ii].x; o0.y = o0.y*e0 + p0*vr[cur][ii].y;
            o0.z = o0.z*e0 + p0*vr[cur][ii].z; o0.w = o0.w*e0 + p0*vr[cur][ii].w;
            l0 = l0*e0 + p0; m0 = mn0;
            float mn1 = fmaxf(m1, d1);
            float e1 = __expf(m1 - mn1), p1 = __expf(d1 - mn1);
            o1.x = o1.x*e1 + p1*vr[cur][ii].x; o1.y = o1.y*e1 + p1*vr[cur][ii].y;
            o1.z = o1.z*e1 + p1*vr[cur][ii].z; o1.w = o1.w*e1 + p1*vr[cur][ii].w;
            l1 = l1*e1 + p1; m1 = mn1;
        }
    }
    if (c == 7 && w == 0 && sub == 0) {
        float4 kv = {0,0,0,0}, vnew = {0,0,0,0};
        #pragma unroll
        for (int sp = 0; sp < 8; ++sp) {
            const float4* pp = QKVP4 + (size_t)(sp * 4 + b) * 512;
            float4 t0 = pp[256 + kvh * 16 + j];
            float4 t1 = pp[384 + kvh * 16 + j];
            kv.x += t0.x; kv.y += t0.y; kv.z += t0.z; kv.w += t0.w;
            vnew.x += t1.x; vnew.y += t1.y; vnew.z += t1.z; vnew.w += t1.w;
        }
        float4 kp;
        kp.x = __shfl_xor(kv.x, 8); kp.y = __shfl_xor(kv.y, 8);
        kp.z = __shfl_xor(kv.z, 8); kp.w = __shfl_xor(kv.w, 8);
        kv.x = kv.x * cs4[0] + sgn * kp.x * sn4[0];
        kv.y = kv.y * cs4[1] + sgn * kp.y * sn4[1];
        kv.z = kv.z * cs4[2] + sgn * kp.z * sn4[2];
        kv.w = kv.w * cs4[3] + sgn * kp.w * sn4[3];
        nk4[(size_t)2048 * 16 + j] = kv;
        nv4[(size_t)2048 * 16 + j] = vnew;
        float d0 = kv.x*q0.x + kv.y*q0.y + kv.z*q0.z + kv.w*q0.w;
        float d1 = kv.x*q1.x + kv.y*q1.y + kv.z*q1.z + kv.w*q1.w;
        d0 += __shfl_xor(d0, 1); d0 += __shfl_xor(d0, 2);
        d0 += __shfl_xor(d0, 4); d0 += __shfl_xor(d0, 8);
        d1 += __shfl_xor(d1, 1); d1 += __shfl_xor(d1, 2);
        d1 += __shfl_xor(d1, 4); d1 += __shfl_xor(d1, 8);
        d0 *= SCALE; d1 *= SCALE;
        float mn0 = fmaxf(m0, d0);
        float e0 = __expf(m0 - mn0), p0 = __expf(d0 - mn0);
        o0.x = o0.x*e0 + p0*vnew.x; o0.y = o0.y*e0 + p0*vnew.y;
        o0.z = o0.z*e0 + p0*vnew.z; o0.w = o0.w*e0 + p0*vnew.w;
        l0 = l0*e0 + p0; m0 = mn0;
        float mn1 = fmaxf(m1, d1);
        float e1 = __expf(m1 - mn1), p1 = __expf(d1 - mn1);
        o1.x = o1.x*e1 + p1*vnew.x; o1.y = o1.y*e1 + p1*vnew.y;
        o1.z = o1.z*e1 + p1*vnew.z; o1.w = o1.w*e1 + p1*vnew.w;
        l1 = l1*e1 + p1; m1 = mn1;
    }
    const int grp = w * 4 + sub;
    oac[0][grp][j] = o0;
    oac[1][grp][j] = o1;
    if (j == 0) {
        mlm[0][grp] = m0; mll[0][grp] = l0;
        mlm[1][grp] = m1; mll[1][grp] = l1;
    }
    __syncthreads();
    if (tid < 128) {
        const int h = tid >> 6, d = tid & 63;
        const float* oa = (const float*)&oac[h][0][0];   // [16][64]
        float M = -1e30f;
        #pragma unroll
        for (int g2 = 0; g2 < 16; ++g2) M = fmaxf(M, mlm[h][g2]);
        float ot = 0.f, lt = 0.f;
        #pragma unroll
        for (int g2 = 0; g2 < 16; ++g2) {
            float e = __expf(mlm[h][g2] - M);
            ot += oa[g2 * 64 + d] * e;
            lt += mll[h][g2] * e;
        }
        int pbase = WS_OPART + ((b * 8 + kvh) * 8 + c) * 132;
        ws[pbase + h * 64 + d] = ot;
        if (d == 0) { ws[pbase + 128 + 2 * h] = M; ws[pbase + 129 + 2 * h] = lt; }
    }
}

// ===== C: chunk-combine (8) + O-proj GEMV (8 k-splits of 128 rows). grid 34, block 512 =====
__global__ __launch_bounds__(512) void k_c(const float* __restrict__ wo,
                                           float* __restrict__ ws, int l) {
    float4* ws4 = (float4*)ws;
    const int tid = threadIdx.x, w = tid >> 6, lane = tid & 63;
    if (blockIdx.x >= 32) {             // zero YMLP
        float4 z = {0,0,0,0};
        ws4[(WS_YMLP >> 2) + (blockIdx.x - 32) * 512 + tid] = z;
        return;
    }
    __shared__ float xs[4][128];
    __shared__ float4 red[8][64][4];
    const int xt = blockIdx.x & 3, s = blockIdx.x >> 2;
    {
        const int bb = tid >> 7, rr = tid & 127;
        const int r = s * 128 + rr;
        const int kvh = r >> 7, g = (r >> 6) & 1, d = r & 63;
        const float* bp = ws + WS_OPART + (size_t)((bb * 8 + kvh) * 8) * 132;
        float m = -1e30f;
        #pragma unroll
        for (int cc = 0; cc < 8; ++cc)
            m = fmaxf(m, bp[cc * 132 + 128 + 2 * g]);
        float lt = 0.f, ot = 0.f;
        #pragma unroll
        for (int cc = 0; cc < 8; ++cc) {
            float f = __expf(bp[cc * 132 + 128 + 2 * g] - m);
            lt += bp[cc * 132 + 129 + 2 * g] * f;
            ot += bp[cc * 132 + g * 64 + d] * f;
        }
        xs[bb][rr] = ot / lt;
    }
    __syncthreads();
    const float4* W4 = (const float4*)(wo + (size_t)l * 1024 * 1024 + xt * 256 + lane * 4);
    float4 a0 = {0,0,0,0}, a1 = a0, a2 = a0, a3 = a0;
    #pragma unroll
    for (int ch = 0; ch < 2; ++ch) {
        float4 wr[8];
        #pragma unroll
        for (int i = 0; i < 8; ++i)
            wr[i] = W4[(size_t)(s * 128 + w * 16 + ch * 8 + i) * 256];
        #pragma unroll
        for (int i = 0; i < 8; ++i) {
            int r = w * 16 + ch * 8 + i;
            fma4(a0, xs[0][r], wr[i]); fma4(a1, xs[1][r], wr[i]);
            fma4(a2, xs[2][r], wr[i]); fma4(a3, xs[3][r], wr[i]);
        }
    }
    red[w][lane][0] = a0; red[w][lane][1] = a1;
    red[w][lane][2] = a2; red[w][lane][3] = a3;
    __syncthreads();
    if (w == 0) {
        int c = xt * 256 + lane * 4;
        #pragma unroll
        for (int b = 0; b < 4; ++b) {
            float4 sv = red[0][lane][b];
            #pragma unroll
            for (int ww = 1; ww < 8; ++ww) {
                float4 t = red[ww][lane][b];
                sv.x += t.x; sv.y += t.y; sv.z += t.z; sv.w += t.w;
            }
            atomicAdd(&ws[WS_YO + b * 1024 + c + 0], sv.x);
            atomicAdd(&ws[WS_YO + b * 1024 + c + 1], sv.y);
            atomicAdd(&ws[WS_YO + b * 1024 + c + 2], sv.z);
            atomicAdd(&ws[WS_YO + b * 1024 + c + 3], sv.w);
        }
    }
}

// ===== D: rms2 recompute + gate AND up GEMV (16 k-splits of 64 rows). grid (16,16), block 512 =====
__global__ __launch_bounds__(512) void k_d(const float* __restrict__ ln2,
                                           const float* __restrict__ wg,
                                           const float* __restrict__ wu,
                                           float* __restrict__ ws, int l) {
    float4* ws4 = (float4*)ws;
    const int tid = threadIdx.x, w = tid >> 6, lane = tid & 63;
    __shared__ float xs[4][64];
    __shared__ float4 red[8][64][4];
    __shared__ float sred[8][4];
    const int t16 = blockIdx.x, y = blockIdx.y;   // y: 0..15 k-split
    const int t2 = tid & 255;

    float4 hn[4]; float ss[4];
    #pragma unroll
    for (int b = 0; b < 4; ++b) {
        float4 h = ws4[(WS_HB >> 2) + b * 256 + t2];
        float4 yv = ws4[(WS_YO >> 2) + b * 256 + t2];
        h.x = fmaf(MUP, yv.x, h.x); h.y = fmaf(MUP, yv.y, h.y);
        h.z = fmaf(MUP, yv.z, h.z); h.w = fmaf(MUP, yv.w, h.w);
        hn[b] = h;
        ss[b] = h.x*h.x + h.y*h.y + h.z*h.z + h.w*h.w;
    }
    #pragma unroll
    for (int b = 0; b < 4; ++b) {
        float v = wsum64(ss[b]);
        if (lane == 0) sred[w][b] = v;
    }
    __syncthreads();
    float rstd[4];
    #pragma unroll
    for (int b = 0; b < 4; ++b) {
        float tot = 0.f;
        #pragma unroll
        for (int ww = 0; ww < 8; ++ww) tot += sred[ww][b];
        rstd[b] = rsqrtf(tot * (1.f/2048.f) + EPS);
    }
    if (blockIdx.x == 0 && blockIdx.y == 0 && tid < 256) {
        #pragma unroll
        for (int b = 0; b < 4; ++b) ws4[(WS_HA >> 2) + b * 256 + t2] = hn[b];
    }
    {
        int tl = t2 - y * 16;
        if (tl >= 0 && tl < 16) {
            float4 g4 = ((const float4*)ln2)[l * 256 + t2];
            #pragma unroll
            for (int b = 0; b < 4; ++b) {
                float4 xv;
                xv.x = hn[b].x * rstd[b] * g4.x; xv.y = hn[b].y * rstd[b] * g4.y;
                xv.z = hn[b].z * rstd[b] * g4.z; xv.w = hn[b].w * rstd[b] * g4.w;
                ((float4*)xs[b])[tl] = xv;
            }
        }
    }
    __syncthreads();
    float4* GUP4 = ws4 + (WS_GUP >> 2);

    #pragma unroll
    for (int mat = 0; mat < 2; ++mat) {
        const float* Wm = (mat ? wu : wg) + (size_t)l * 1024 * 4096;
        const float4* W4 = (const float4*)(Wm + t16 * 256 + lane * 4);
        float4 wr[8];
        #pragma unroll
        for (int i = 0; i < 8; ++i)
            wr[i] = W4[(size_t)(y * 64 + w * 8 + i) * 1024];
        float4 a0 = {0,0,0,0}, a1 = a0, a2 = a0, a3 = a0;
        #pragma unroll
        for (int i = 0; i < 8; ++i) {
            int r = w * 8 + i;
            fma4(a0, xs[0][r], wr[i]); fma4(a1, xs[1][r], wr[i]);
            fma4(a2, xs[2][r], wr[i]); fma4(a3, xs[3][r], wr[i]);
        }
        red[w][lane][0] = a0; red[w][lane][1] = a1;
        red[w][lane][2] = a2; red[w][lane][3] = a3;
        __syncthreads();
        if (w == 0) {
            #pragma unroll
            for (int b = 0; b < 4; ++b) {
                float4 sv = red[0][lane][b];
                #pragma unroll
                for (int ww = 1; ww < 8; ++ww) {
                    float4 t = red[ww][lane][b];
                    sv.x += t.x; sv.y += t.y; sv.z += t.z; sv.w += t.w;
                }
                GUP4[(size_t)((mat * 16 + y) * 4 + b) * 1024 + t16 * 64 + lane] = sv;
            }
        }
        __syncthreads();
    }
}

// ===== E: silu-combine (16 partials) + down GEMV (32 f-splits of 128 rows). grid (4,32), block 512 =====
__global__ __launch_bounds__(512) void k_e(const float* __restrict__ wd,
                                           float* __restrict__ ws, int l) {
    float4* ws4 = (float4*)ws;
    const int tid = threadIdx.x, w = tid >> 6, lane = tid & 63;
    __shared__ float ts[4][128];
    __shared__ float4 red[8][64][4];
    const int xt = blockIdx.x, s = blockIdx.y;
    if (tid < 128) {
        const int bb = tid >> 5, i = tid & 31;
        const int f4 = s * 32 + i;
        const float4* GUP4 = (const float4*)ws4 + (WS_GUP >> 2);
        float4 g = {0,0,0,0}, u = {0,0,0,0};
        #pragma unroll
        for (int sp = 0; sp < 16; ++sp) {
            float4 gv = GUP4[(size_t)(sp * 4 + bb) * 1024 + f4];
            float4 uv = GUP4[(size_t)((16 + sp) * 4 + bb) * 1024 + f4];
            g.x += gv.x; g.y += gv.y; g.z += gv.z; g.w += gv.w;
            u.x += uv.x; u.y += uv.y; u.z += uv.z; u.w += uv.w;
        }
        float4 t;
        t.x = (g.x / (1.f + __expf(-g.x))) * u.x;
        t.y = (g.y / (1.f + __expf(-g.y))) * u.y;
        t.z = (g.z / (1.f + __expf(-g.z))) * u.z;
        t.w = (g.w / (1.f + __expf(-g.w))) * u.w;
        ((float4*)ts[bb])[i] = t;
    }
    __syncthreads();
    const float4* W4 = (const float4*)(wd + (size_t)l * 4096 * 1024 + xt * 256 + lane * 4);
    float4 a0 = {0,0,0,0}, a1 = a0, a2 = a0, a3 = a0;
    #pragma unroll
    for (int ch = 0; ch < 2; ++ch) {
        float4 wr[8];
        #pragma unroll
        for (int i = 0; i < 8; ++i)
            wr[i] = W4[(size_t)(s * 128 + w * 16 + ch * 8 + i) * 256];
        #pragma unroll
        for (int i = 0; i < 8; ++i) {
            int r = w * 16 + ch * 8 + i;
            fma4(a0, ts[0][r], wr[i]); fma4(a1, ts[1][r], wr[i]);
            fma4(a2, ts[2][r], wr[i]); fma4(a3, ts[3][r], wr[i]);
        }
    }
    red[w][lane][0] = a0; red[w][lane][1] = a1;
    red[w][lane][2] = a2; red[w][lane][3] = a3;
    __syncthreads();
    if (w == 0) {
        int c = xt * 256 + lane * 4;
        #pragma unroll
        for (int b = 0; b < 4; ++b) {
            float4 sv = red[0][lane][b];
            #pragma unroll
            for (int ww = 1; ww < 8; ++ww) {
                float4 t = red[ww][lane][b];
                sv.x += t.x; sv.y += t.y; sv.z += t.z; sv.w += t.w;
            }
            atomicAdd(&ws[WS_YMLP + b * 1024 + c + 0], sv.x);
            atomicAdd(&ws[WS_YMLP + b * 1024 + c + 1], sv.y);
            atomicAdd(&ws[WS_YMLP + b * 1024 + c + 2], sv.z);
            atomicAdd(&ws[WS_YMLP + b * 1024 + c + 3], sv.w);
        }
    }
}

__global__ __launch_bounds__(256) void k_final(const float* __restrict__ normw,
                                               float* __restrict__ ws,
                                               float* __restrict__ out) {
    float4* ws4 = (float4*)ws;
    int tid = threadIdx.x;
    int b = blockIdx.x, w = tid >> 6, lane = tid & 63;
    __shared__ float sred[4];
    float4 h = ws4[(WS_HA >> 2) + b * 256 + tid];
    float4 y = ws4[(WS_YMLP >> 2) + b * 256 + tid];
    h.x = fmaf(MUP, y.x, h.x); h.y = fmaf(MUP, y.y, h.y);
    h.z = fmaf(MUP, y.z, h.z); h.w = fmaf(MUP, y.w, h.w);
    float ssv = h.x*h.x + h.y*h.y + h.z*h.z + h.w*h.w;
    float v = wsum64(ssv);
    if (lane == 0) sred[w] = v;
    __syncthreads();
    float rstd = rsqrtf((sred[0] + sred[1] + sred[2] + sred[3]) * (1.f/1024.f) + EPS);
    float4 g4 = ((const float4*)normw)[tid];
    float4 o;
    o.x = h.x * rstd * g4.x; o.y = h.y * rstd * g4.y;
    o.z = h.z * rstd * g4.z; o.w = h.w * rstd * g4.w;
    ((float4*)out)[b * 256 + tid] = o;
}

extern "C" void kernel_launch(void* const* d_in, const int* in_sizes, int n_in,
                              void* d_out, int out_size, void* d_ws, size_t ws_size,
                              hipStream_t stream) {
    const float* emb  = (const float*)d_in[0];
    const float* kc   = (const float*)d_in[1];
    const float* vc   = (const float*)d_in[2];
    const float* ln1  = (const float*)d_in[3];
    const float* ln2  = (const float*)d_in[4];
    const float* nrmw = (const float*)d_in[5];
    const float* wq   = (const float*)d_in[6];
    const float* wk   = (const float*)d_in[7];
    const float* wv   = (const float*)d_in[8];
    const float* wo   = (const float*)d_in[9];
    const float* wg   = (const float*)d_in[10];
    const float* wu   = (const float*)d_in[11];
    const float* wd   = (const float*)d_in[12];
    const int*   cl   = (const int*)d_in[13];

    float* out = (float*)d_out;
    float* ws  = (float*)d_ws;
    float* nk  = out + OUT_NK;
    float* nv  = out + OUT_NV;

    k_init<<<3, 256, 0, stream>>>(emb, cl, ws, out);
    for (int l = 0; l < 16; ++l) {
        k_a<<<66, 512, 0, stream>>>(ln1, wq, wk, wv, ws, l);
        k_b<<<256, 256, 0, stream>>>(kc, vc, cl, ws, nk, nv, l);
        k_c<<<34, 512, 0, stream>>>(wo, ws, l);
        k_d<<<dim3(16, 16), 512, 0, stream>>>(ln2, wg, wu, ws, l);
        k_e<<<dim3(4, 32), 512, 0, stream>>>(wd, ws, l);
    }
    k_final<<<4, 256, 0, stream>>>(nrmw, ws, out);
}

// Round 13
// 882.355 us; speedup vs baseline: 1.0522x; 1.0186x over previous
//
#include <hip/hip_runtime.h>
#include <math.h>

#define MUP 0.35f       // 1.4/sqrt(16)
#define SCALE 0.125f    // 1/sqrt(64)
#define EPS 1e-5f

typedef float f32x4 __attribute__((ext_vector_type(4)));

// workspace float offsets
#define WS_HA    0          // [4][1024] h at layer entry
#define WS_HB    4096       // [4][1024] h after attn residual input
#define WS_YMLP  8192       // [4][1024] atomic accum
#define WS_YO    12288      // [4][1024] atomic accum
#define WS_QKVP  16384      // [8][4][2048] qkv k-split partials
#define WS_OPART 278528     // [4][8][8][132] attn chunk partials
#define WS_GUP   413696     // [2][8][4][4096] gate/up k-split partials

// d_out float offsets
#define OUT_NK  4096
#define OUT_NV  (4096 + 16*4*8*2049*64)
#define OUT_SC  (4096 + 2*16*4*8*2049*64)

__device__ __forceinline__ float wsum64(float v) {
    v += __shfl_xor(v, 32); v += __shfl_xor(v, 16); v += __shfl_xor(v, 8);
    v += __shfl_xor(v, 4);  v += __shfl_xor(v, 2);  v += __shfl_xor(v, 1);
    return v;
}

__device__ __forceinline__ void fma4(float4& a, float s, const float4 w) {
    a.x = fmaf(s, w.x, a.x); a.y = fmaf(s, w.y, a.y);
    a.z = fmaf(s, w.z, a.z); a.w = fmaf(s, w.w, a.w);
}

__device__ __forceinline__ void nt_store4(const float4 v, float4* p) {
    f32x4 t = {v.x, v.y, v.z, v.w};
    __builtin_nontemporal_store(t, (f32x4*)p);
}

__global__ __launch_bounds__(256) void k_init(const float* __restrict__ emb,
                                              const int* __restrict__ cl,
                                              float* __restrict__ ws,
                                              float* __restrict__ out) {
    int tid = threadIdx.x;
    float4* ws4 = (float4*)ws;
    float4 z = {0.f, 0.f, 0.f, 0.f};
    if (blockIdx.x == 0) {
        const float4* e4 = (const float4*)emb;
        #pragma unroll
        for (int k = 0; k < 4; ++k) ws4[(WS_HA >> 2) + k * 256 + tid] = e4[k * 256 + tid];
        if (tid == 0) out[OUT_SC] = (float)(cl[0] + 1);
    } else if (blockIdx.x == 1) {
        #pragma unroll
        for (int k = 0; k < 4; ++k) ws4[(WS_YMLP >> 2) + k * 256 + tid] = z;
    } else {
        #pragma unroll
        for (int k = 0; k < 4; ++k) ws4[(WS_YO >> 2) + k * 256 + tid] = z;
    }
}

// ===== A: rms1 recompute + QKV GEMV (8 k-splits of 128 rows). grid 66, block 512 =====
__global__ __launch_bounds__(512) void k_a(const float* __restrict__ ln1,
                                           const float* __restrict__ wq,
                                           const float* __restrict__ wk,
                                           const float* __restrict__ wv,
                                           float* __restrict__ ws, int l) {
    float4* ws4 = (float4*)ws;
    const int tid = threadIdx.x, w = tid >> 6, lane = tid & 63;
    if (blockIdx.x >= 64) {             // zero YO (2 blocks x 512 float4)
        float4 z = {0,0,0,0};
        ws4[(WS_YO >> 2) + (blockIdx.x - 64) * 512 + tid] = z;
        return;
    }
    __shared__ float xs[4][128];
    __shared__ float4 red[8][64][4];
    __shared__ float sred[8][4];
    const int s = blockIdx.x >> 3, xt = blockIdx.x & 7;   // s: 0..7 k-split
    const int t2 = tid & 255;

    float4 hn[4]; float ss[4];
    #pragma unroll
    for (int b = 0; b < 4; ++b) {
        float4 h = ws4[(WS_HA >> 2) + b * 256 + t2];
        float4 y = ws4[(WS_YMLP >> 2) + b * 256 + t2];
        h.x = fmaf(MUP, y.x, h.x); h.y = fmaf(MUP, y.y, h.y);
        h.z = fmaf(MUP, y.z, h.z); h.w = fmaf(MUP, y.w, h.w);
        hn[b] = h;
        ss[b] = h.x*h.x + h.y*h.y + h.z*h.z + h.w*h.w;
    }
    #pragma unroll
    for (int b = 0; b < 4; ++b) {
        float v = wsum64(ss[b]);
        if (lane == 0) sred[w][b] = v;
    }
    __syncthreads();
    float rstd[4];
    #pragma unroll
    for (int b = 0; b < 4; ++b) {
        float tot = 0.f;
        #pragma unroll
        for (int ww = 0; ww < 8; ++ww) tot += sred[ww][b];
        rstd[b] = rsqrtf(tot * (1.f/2048.f) + EPS);   // 2x redundant sum
    }
    if (blockIdx.x == 0 && tid < 256) {
        #pragma unroll
        for (int b = 0; b < 4; ++b) ws4[(WS_HB >> 2) + b * 256 + t2] = hn[b];
    }
    {
        int tl = t2 - s * 32;
        if (tl >= 0 && tl < 32) {
            float4 g4 = ((const float4*)ln1)[l * 256 + t2];
            #pragma unroll
            for (int b = 0; b < 4; ++b) {
                float4 xv;
                xv.x = hn[b].x * rstd[b] * g4.x; xv.y = hn[b].y * rstd[b] * g4.y;
                xv.z = hn[b].z * rstd[b] * g4.z; xv.w = hn[b].w * rstd[b] * g4.w;
                ((float4*)xs[b])[tl] = xv;
            }
        }
    }
    __syncthreads();

    const float* Wp; int nc, c;
    if (xt < 4)      { Wp = wq + (size_t)l * 1024 * 1024; nc = 1024; c = xt * 256 + lane * 4; }
    else if (xt < 6) { Wp = wk + (size_t)l * 1024 * 512;  nc = 512;  c = (xt - 4) * 256 + lane * 4; }
    else             { Wp = wv + (size_t)l * 1024 * 512;  nc = 512;  c = (xt - 6) * 256 + lane * 4; }
    const float4* W4 = (const float4*)(Wp + c);
    const size_t nc4 = (size_t)(nc >> 2);
    float4 a0 = {0,0,0,0}, a1 = a0, a2 = a0, a3 = a0;
    #pragma unroll
    for (int ch = 0; ch < 2; ++ch) {
        float4 wr[8];
        #pragma unroll
        for (int i = 0; i < 8; ++i)
            wr[i] = W4[(size_t)(s * 128 + w * 16 + ch * 8 + i) * nc4];
        #pragma unroll
        for (int i = 0; i < 8; ++i) {
            int r = w * 16 + ch * 8 + i;
            fma4(a0, xs[0][r], wr[i]); fma4(a1, xs[1][r], wr[i]);
            fma4(a2, xs[2][r], wr[i]); fma4(a3, xs[3][r], wr[i]);
        }
    }
    red[w][lane][0] = a0; red[w][lane][1] = a1;
    red[w][lane][2] = a2; red[w][lane][3] = a3;
    __syncthreads();
    if (w == 0) {
        float4* QKVP4 = ws4 + (WS_QKVP >> 2);
        #pragma unroll
        for (int b = 0; b < 4; ++b) {
            float4 sv = red[0][lane][b];
            #pragma unroll
            for (int ww = 1; ww < 8; ++ww) {
                float4 t = red[ww][lane][b];
                sv.x += t.x; sv.y += t.y; sv.z += t.z; sv.w += t.w;
            }
            QKVP4[(size_t)(s * 4 + b) * 512 + xt * 64 + lane] = sv;
        }
    }
}

// ===== B: single-pass flash-decode + fused cache copy, pipelined. grid 256, block 256 =====
__global__ __launch_bounds__(256) void k_b(const float* __restrict__ kc,
                                           const float* __restrict__ vc,
                                           const int* __restrict__ cl,
                                           float* __restrict__ ws,
                                           float* __restrict__ nk,
                                           float* __restrict__ nv, int l) {
    const int bid = blockIdx.x;
    const int b = bid >> 6, kvh = (bid >> 3) & 7, c = bid & 7;
    const int s0 = c * 256;
    const int tid = threadIdx.x, w = tid >> 6, lane = tid & 63;
    const int sub = lane >> 4, j = lane & 15;
    float4* ws4 = (float4*)ws;
    const float4* QKVP4 = (const float4*)ws4 + (WS_QKVP >> 2);

    __shared__ float4 oac[2][16][16];   // [head][group][j]
    __shared__ float mlm[2][16], mll[2][16];

    const float pos = (float)cl[0];
    float cs4[4], sn4[4];
    #pragma unroll
    for (int m = 0; m < 4; ++m) {
        float t = (float)(4 * (j & 7) + m);
        float fr = pos * __expf(-t * 0.2878231366242557f);  // ln(1e4)/32
        cs4[m] = cosf(fr); sn4[m] = sinf(fr);
    }
    const float sgn = (j < 8) ? -1.f : 1.f;

    // q reduce over 8 k-split partials + RoPE
    float4 q0 = {0,0,0,0}, q1 = {0,0,0,0};
    #pragma unroll
    for (int sp = 0; sp < 8; ++sp) {
        const float4* qp = QKVP4 + (size_t)(sp * 4 + b) * 512 + kvh * 32;
        float4 t0 = qp[j], t1 = qp[16 + j];
        q0.x += t0.x; q0.y += t0.y; q0.z += t0.z; q0.w += t0.w;
        q1.x += t1.x; q1.y += t1.y; q1.z += t1.z; q1.w += t1.w;
    }
    {
        float4 q0p, q1p;
        q0p.x = __shfl_xor(q0.x, 8); q0p.y = __shfl_xor(q0.y, 8);
        q0p.z = __shfl_xor(q0.z, 8); q0p.w = __shfl_xor(q0.w, 8);
        q1p.x = __shfl_xor(q1.x, 8); q1p.y = __shfl_xor(q1.y, 8);
        q1p.z = __shfl_xor(q1.z, 8); q1p.w = __shfl_xor(q1.w, 8);
        q0.x = q0.x * cs4[0] + sgn * q0p.x * sn4[0];
        q0.y = q0.y * cs4[1] + sgn * q0p.y * sn4[1];
        q0.z = q0.z * cs4[2] + sgn * q0p.z * sn4[2];
        q0.w = q0.w * cs4[3] + sgn * q0p.w * sn4[3];
        q1.x = q1.x * cs4[0] + sgn * q1p.x * sn4[0];
        q1.y = q1.y * cs4[1] + sgn * q1p.y * sn4[1];
        q1.z = q1.z * cs4[2] + sgn * q1p.z * sn4[2];
        q1.w = q1.w * cs4[3] + sgn * q1p.w * sn4[3];
    }

    const size_t cbase = (size_t)((l * 4 + b) * 8 + kvh);
    const float4* kc4 = (const float4*)kc + cbase * 2048 * 16;
    const float4* vc4 = (const float4*)vc + cbase * 2048 * 16;
    float4* nk4 = (float4*)nk + cbase * 2049 * 16;
    float4* nv4 = (float4*)nv + cbase * 2049 * 16;

    float m0 = -1e30f, m1 = -1e30f, l0 = 0.f, l1 = 0.f;
    float4 o0 = {0,0,0,0}, o1 = {0,0,0,0};
    float4 kr[2][4], vr[2][4];

    // prologue: load group 0
    #pragma unroll
    for (int ii = 0; ii < 4; ++ii) {
        int r = s0 + w * 16 + ii * 4 + sub;
        kr[0][ii] = kc4[(size_t)r * 16 + j];
        vr[0][ii] = vc4[(size_t)r * 16 + j];
    }
    #pragma unroll
    for (int g = 0; g < 4; ++g) {
        const int cur = g & 1, nxt = cur ^ 1;
        const int rb = s0 + g * 64 + w * 16;
        if (g < 3) {
            const int rn = s0 + (g + 1) * 64 + w * 16;
            #pragma unroll
            for (int ii = 0; ii < 4; ++ii) {
                int r = rn + ii * 4 + sub;
                kr[nxt][ii] = kc4[(size_t)r * 16 + j];
                vr[nxt][ii] = vc4[(size_t)r * 16 + j];
            }
        }
        #pragma unroll
        for (int ii = 0; ii < 4; ++ii) {
            int r = rb + ii * 4 + sub;
            nt_store4(kr[cur][ii], &nk4[(size_t)r * 16 + j]);
            nt_store4(vr[cur][ii], &nv4[(size_t)r * 16 + j]);
        }
        #pragma unroll
        for (int ii = 0; ii < 4; ++ii) {
            float4 kv = kr[cur][ii];
            float d0 = kv.x*q0.x + kv.y*q0.y + kv.z*q0.z + kv.w*q0.w;
            float d1 = kv.x*q1.x + kv.y*q1.y + kv.z*q1.z + kv.w*q1.w;
            d0 += __shfl_xor(d0, 1); d0 += __shfl_xor(d0, 2);
            d0 += __shfl_xor(d0, 4); d0 += __shfl_xor(d0, 8);
            d1 += __shfl_xor(d1, 1); d1 += __shfl_xor(d1, 2);
            d1 += __shfl_xor(d1, 4); d1 += __shfl_xor(d1, 8);
            d0 *= SCALE; d1 *= SCALE;
            float mn0 = fmaxf(m0, d0);
            float e0 = __expf(m0 - mn0), p0 = __expf(d0 - mn0);
            o0.x = o0.x*e0 + p0*vr[cur][ii].x; o0.y = o0.y*e0 + p0*vr[cur][ii].y;
            o0.z = o0.z*e0 + p0*vr[cur][ii].z; o0.w = o0.w*e0 + p0*vr[cur][ii].w;
            l0 = l0*e0 + p0; m0 = mn0;
            float mn1 = fmaxf(m1, d1);
            float e1 = __expf(m1 - mn1), p1 = __expf(d1 - mn1);
            o1.x = o1.x*e1 + p1*vr[cur][ii].x; o1.y = o1.y*e1 + p1*vr[cur][ii].y;
            o1.z = o1.z*e1 + p1*vr[cur][ii].z; o1.w = o1.w*e1 + p1*vr[cur][ii].w;
            l1 = l1*e1 + p1; m1 = mn1;
        }
    }
    if (c == 7 && w == 0 && sub == 0) {
        float4 kv = {0,0,0,0}, vnew = {0,0,0,0};
        #pragma unroll
        for (int sp = 0; sp < 8; ++sp) {
            const float4* pp = QKVP4 + (size_t)(sp * 4 + b) * 512;
            float4 t0 = pp[256 + kvh * 16 + j];
            float4 t1 = pp[384 + kvh * 16 + j];
            kv.x += t0.x; kv.y += t0.y; kv.z += t0.z; kv.w += t0.w;
            vnew.x += t1.x; vnew.y += t1.y; vnew.z += t1.z; vnew.w += t1.w;
        }
        float4 kp;
        kp.x = __shfl_xor(kv.x, 8); kp.y = __shfl_xor(kv.y, 8);
        kp.z = __shfl_xor(kv.z, 8); kp.w = __shfl_xor(kv.w, 8);
        kv.x = kv.x * cs4[0] + sgn * kp.x * sn4[0];
        kv.y = kv.y * cs4[1] + sgn * kp.y * sn4[1];
        kv.z = kv.z * cs4[2] + sgn * kp.z * sn4[2];
        kv.w = kv.w * cs4[3] + sgn * kp.w * sn4[3];
        nk4[(size_t)2048 * 16 + j] = kv;
        nv4[(size_t)2048 * 16 + j] = vnew;
        float d0 = kv.x*q0.x + kv.y*q0.y + kv.z*q0.z + kv.w*q0.w;
        float d1 = kv.x*q1.x + kv.y*q1.y + kv.z*q1.z + kv.w*q1.w;
        d0 += __shfl_xor(d0, 1); d0 += __shfl_xor(d0, 2);
        d0 += __shfl_xor(d0, 4); d0 += __shfl_xor(d0, 8);
        d1 += __shfl_xor(d1, 1); d1 += __shfl_xor(d1, 2);
        d1 += __shfl_xor(d1, 4); d1 += __shfl_xor(d1, 8);
        d0 *= SCALE; d1 *= SCALE;
        float mn0 = fmaxf(m0, d0);
        float e0 = __expf(m0 - mn0), p0 = __expf(d0 - mn0);
        o0.x = o0.x*e0 + p0*vnew.x; o0.y = o0.y*e0 + p0*vnew.y;
        o0.z = o0.z*e0 + p0*vnew.z; o0.w = o0.w*e0 + p0*vnew.w;
        l0 = l0*e0 + p0; m0 = mn0;
        float mn1 = fmaxf(m1, d1);
        float e1 = __expf(m1 - mn1), p1 = __expf(d1 - mn1);
        o1.x = o1.x*e1 + p1*vnew.x; o1.y = o1.y*e1 + p1*vnew.y;
        o1.z = o1.z*e1 + p1*vnew.z; o1.w = o1.w*e1 + p1*vnew.w;
        l1 = l1*e1 + p1; m1 = mn1;
    }
    const int grp = w * 4 + sub;
    oac[0][grp][j] = o0;
    oac[1][grp][j] = o1;
    if (j == 0) {
        mlm[0][grp] = m0; mll[0][grp] = l0;
        mlm[1][grp] = m1; mll[1][grp] = l1;
    }
    __syncthreads();
    if (tid < 128) {
        const int h = tid >> 6, d = tid & 63;
        const float* oa = (const float*)&oac[h][0][0];   // [16][64]
        float M = -1e30f;
        #pragma unroll
        for (int g2 = 0; g2 < 16; ++g2) M = fmaxf(M, mlm[h][g2]);
        float ot = 0.f, lt = 0.f;
        #pragma unroll
        for (int g2 = 0; g2 < 16; ++g2) {
            float e = __expf(mlm[h][g2] - M);
            ot += oa[g2 * 64 + d] * e;
            lt += mll[h][g2] * e;
        }
        int pbase = WS_OPART + ((b * 8 + kvh) * 8 + c) * 132;
        ws[pbase + h * 64 + d] = ot;
        if (d == 0) { ws[pbase + 128 + 2 * h] = M; ws[pbase + 129 + 2 * h] = lt; }
    }
}

// ===== C: chunk-combine (8) + O-proj GEMV (8 k-splits of 128 rows). grid 34, block 512 =====
__global__ __launch_bounds__(512) void k_c(const float* __restrict__ wo,
                                           float* __restrict__ ws, int l) {
    float4* ws4 = (float4*)ws;
    const int tid = threadIdx.x, w = tid >> 6, lane = tid & 63;
    if (blockIdx.x >= 32) {             // zero YMLP
        float4 z = {0,0,0,0};
        ws4[(WS_YMLP >> 2) + (blockIdx.x - 32) * 512 + tid] = z;
        return;
    }
    __shared__ float xs[4][128];
    __shared__ float4 red[8][64][4];
    const int xt = blockIdx.x & 3, s = blockIdx.x >> 2;
    {
        const int bb = tid >> 7, rr = tid & 127;
        const int r = s * 128 + rr;
        const int kvh = r >> 7, g = (r >> 6) & 1, d = r & 63;
        const float* bp = ws + WS_OPART + (size_t)((bb * 8 + kvh) * 8) * 132;
        float m = -1e30f;
        #pragma unroll
        for (int cc = 0; cc < 8; ++cc)
            m = fmaxf(m, bp[cc * 132 + 128 + 2 * g]);
        float lt = 0.f, ot = 0.f;
        #pragma unroll
        for (int cc = 0; cc < 8; ++cc) {
            float f = __expf(bp[cc * 132 + 128 + 2 * g] - m);
            lt += bp[cc * 132 + 129 + 2 * g] * f;
            ot += bp[cc * 132 + g * 64 + d] * f;
        }
        xs[bb][rr] = ot / lt;
    }
    __syncthreads();
    const float4* W4 = (const float4*)(wo + (size_t)l * 1024 * 1024 + xt * 256 + lane * 4);
    float4 a0 = {0,0,0,0}, a1 = a0, a2 = a0, a3 = a0;
    #pragma unroll
    for (int ch = 0; ch < 2; ++ch) {
        float4 wr[8];
        #pragma unroll
        for (int i = 0; i < 8; ++i)
            wr[i] = W4[(size_t)(s * 128 + w * 16 + ch * 8 + i) * 256];
        #pragma unroll
        for (int i = 0; i < 8; ++i) {
            int r = w * 16 + ch * 8 + i;
            fma4(a0, xs[0][r], wr[i]); fma4(a1, xs[1][r], wr[i]);
            fma4(a2, xs[2][r], wr[i]); fma4(a3, xs[3][r], wr[i]);
        }
    }
    red[w][lane][0] = a0; red[w][lane][1] = a1;
    red[w][lane][2] = a2; red[w][lane][3] = a3;
    __syncthreads();
    if (w == 0) {
        int c = xt * 256 + lane * 4;
        #pragma unroll
        for (int b = 0; b < 4; ++b) {
            float4 sv = red[0][lane][b];
            #pragma unroll
            for (int ww = 1; ww < 8; ++ww) {
                float4 t = red[ww][lane][b];
                sv.x += t.x; sv.y += t.y; sv.z += t.z; sv.w += t.w;
            }
            atomicAdd(&ws[WS_YO + b * 1024 + c + 0], sv.x);
            atomicAdd(&ws[WS_YO + b * 1024 + c + 1], sv.y);
            atomicAdd(&ws[WS_YO + b * 1024 + c + 2], sv.z);
            atomicAdd(&ws[WS_YO + b * 1024 + c + 3], sv.w);
        }
    }
}

// ===== D: rms2 recompute + gate AND up GEMV (8 k-splits of 128 rows). grid (16,8), block 512 =====
__global__ __launch_bounds__(512) void k_d(const float* __restrict__ ln2,
                                           const float* __restrict__ wg,
                                           const float* __restrict__ wu,
                                           float* __restrict__ ws, int l) {
    float4* ws4 = (float4*)ws;
    const int tid = threadIdx.x, w = tid >> 6, lane = tid & 63;
    __shared__ float xs[4][128];
    __shared__ float4 red[8][64][4];
    __shared__ float sred[8][4];
    const int t16 = blockIdx.x, y = blockIdx.y;
    const int t2 = tid & 255;

    float4 hn[4]; float ss[4];
    #pragma unroll
    for (int b = 0; b < 4; ++b) {
        float4 h = ws4[(WS_HB >> 2) + b * 256 + t2];
        float4 yv = ws4[(WS_YO >> 2) + b * 256 + t2];
        h.x = fmaf(MUP, yv.x, h.x); h.y = fmaf(MUP, yv.y, h.y);
        h.z = fmaf(MUP, yv.z, h.z); h.w = fmaf(MUP, yv.w, h.w);
        hn[b] = h;
        ss[b] = h.x*h.x + h.y*h.y + h.z*h.z + h.w*h.w;
    }
    #pragma unroll
    for (int b = 0; b < 4; ++b) {
        float v = wsum64(ss[b]);
        if (lane == 0) sred[w][b] = v;
    }
    __syncthreads();
    float rstd[4];
    #pragma unroll
    for (int b = 0; b < 4; ++b) {
        float tot = 0.f;
        #pragma unroll
        for (int ww = 0; ww < 8; ++ww) tot += sred[ww][b];
        rstd[b] = rsqrtf(tot * (1.f/2048.f) + EPS);
    }
    if (blockIdx.x == 0 && blockIdx.y == 0 && tid < 256) {
        #pragma unroll
        for (int b = 0; b < 4; ++b) ws4[(WS_HA >> 2) + b * 256 + t2] = hn[b];
    }
    {
        int tl = t2 - y * 32;
        if (tl >= 0 && tl < 32) {
            float4 g4 = ((const float4*)ln2)[l * 256 + t2];
            #pragma unroll
            for (int b = 0; b < 4; ++b) {
                float4 xv;
                xv.x = hn[b].x * rstd[b] * g4.x; xv.y = hn[b].y * rstd[b] * g4.y;
                xv.z = hn[b].z * rstd[b] * g4.z; xv.w = hn[b].w * rstd[b] * g4.w;
                ((float4*)xs[b])[tl] = xv;
            }
        }
    }
    __syncthreads();
    float4* GUP4 = ws4 + (WS_GUP >> 2);

    #pragma unroll
    for (int mat = 0; mat < 2; ++mat) {
        const float* Wm = (mat ? wu : wg) + (size_t)l * 1024 * 4096;
        const float4* W4 = (const float4*)(Wm + t16 * 256 + lane * 4);
        float4 a0 = {0,0,0,0}, a1 = a0, a2 = a0, a3 = a0;
        #pragma unroll
        for (int ch = 0; ch < 2; ++ch) {
            float4 wr[8];
            #pragma unroll
            for (int i = 0; i < 8; ++i)
                wr[i] = W4[(size_t)(y * 128 + w * 16 + ch * 8 + i) * 1024];
            #pragma unroll
            for (int i = 0; i < 8; ++i) {
                int r = w * 16 + ch * 8 + i;
                fma4(a0, xs[0][r], wr[i]); fma4(a1, xs[1][r], wr[i]);
                fma4(a2, xs[2][r], wr[i]); fma4(a3, xs[3][r], wr[i]);
            }
        }
        red[w][lane][0] = a0; red[w][lane][1] = a1;
        red[w][lane][2] = a2; red[w][lane][3] = a3;
        __syncthreads();
        if (w == 0) {
            #pragma unroll
            for (int b = 0; b < 4; ++b) {
                float4 sv = red[0][lane][b];
                #pragma unroll
                for (int ww = 1; ww < 8; ++ww) {
                    float4 t = red[ww][lane][b];
                    sv.x += t.x; sv.y += t.y; sv.z += t.z; sv.w += t.w;
                }
                GUP4[(size_t)((mat * 8 + y) * 4 + b) * 1024 + t16 * 64 + lane] = sv;
            }
        }
        __syncthreads();
    }
}

// ===== E: silu-combine + down GEMV (32 f-splits of 128 rows). grid (4,32), block 512 =====
__global__ __launch_bounds__(512) void k_e(const float* __restrict__ wd,
                                           float* __restrict__ ws, int l) {
    float4* ws4 = (float4*)ws;
    const int tid = threadIdx.x, w = tid >> 6, lane = tid & 63;
    __shared__ float ts[4][128];
    __shared__ float4 red[8][64][4];
    const int xt = blockIdx.x, s = blockIdx.y;
    if (tid < 128) {
        const int bb = tid >> 5, i = tid & 31;
        const int f4 = s * 32 + i;
        const float4* GUP4 = (const float4*)ws4 + (WS_GUP >> 2);
        float4 g = {0,0,0,0}, u = {0,0,0,0};
        #pragma unroll
        for (int sp = 0; sp < 8; ++sp) {
            float4 gv = GUP4[(size_t)(sp * 4 + bb) * 1024 + f4];
            float4 uv = GUP4[(size_t)((8 + sp) * 4 + bb) * 1024 + f4];
            g.x += gv.x; g.y += gv.y; g.z += gv.z; g.w += gv.w;
            u.x += uv.x; u.y += uv.y; u.z += uv.z; u.w += uv.w;
        }
        float4 t;
        t.x = (g.x / (1.f + __expf(-g.x))) * u.x;
        t.y = (g.y / (1.f + __expf(-g.y))) * u.y;
        t.z = (g.z / (1.f + __expf(-g.z))) * u.z;
        t.w = (g.w / (1.f + __expf(-g.w))) * u.w;
        ((float4*)ts[bb])[i] = t;
    }
    __syncthreads();
    const float4* W4 = (const float4*)(wd + (size_t)l * 4096 * 1024 + xt * 256 + lane * 4);
    float4 a0 = {0,0,0,0}, a1 = a0, a2 = a0, a3 = a0;
    #pragma unroll
    for (int ch = 0; ch < 2; ++ch) {
        float4 wr[8];
        #pragma unroll
        for (int i = 0; i < 8; ++i)
            wr[i] = W4[(size_t)(s * 128 + w * 16 + ch * 8 + i) * 256];
        #pragma unroll
        for (int i = 0; i < 8; ++i) {
            int r = w * 16 + ch * 8 + i;
            fma4(a0, ts[0][r], wr[i]); fma4(a1, ts[1][r], wr[i]);
            fma4(a2, ts[2][r], wr[i]); fma4(a3, ts[3][r], wr[i]);
        }
    }
    red[w][lane][0] = a0; red[w][lane][1] = a1;
    red[w][lane][2] = a2; red[w][lane][3] = a3;
    __syncthreads();
    if (w == 0) {
        int c = xt * 256 + lane * 4;
        #pragma unroll
        for (int b = 0; b < 4; ++b) {
            float4 sv = red[0][lane][b];
            #pragma unroll
            for (int ww = 1; ww < 8; ++ww) {
                float4 t = red[ww][lane][b];
                sv.x += t.x; sv.y += t.y; sv.z += t.z; sv.w += t.w;
            }
            atomicAdd(&ws[WS_YMLP + b * 1024 + c + 0], sv.x);
            atomicAdd(&ws[WS_YMLP + b * 1024 + c + 1], sv.y);
            atomicAdd(&ws[WS_YMLP + b * 1024 + c + 2], sv.z);
            atomicAdd(&ws[WS_YMLP + b * 1024 + c + 3], sv.w);
        }
    }
}

__global__ __launch_bounds__(256) void k_final(const float* __restrict__ normw,
                                               float* __restrict__ ws,
                                               float* __restrict__ out) {
    float4* ws4 = (float4*)ws;
    int tid = threadIdx.x;
    int b = blockIdx.x, w = tid >> 6, lane = tid & 63;
    __shared__ float sred[4];
    float4 h = ws4[(WS_HA >> 2) + b * 256 + tid];
    float4 y = ws4[(WS_YMLP >> 2) + b * 256 + tid];
    h.x = fmaf(MUP, y.x, h.x); h.y = fmaf(MUP, y.y, h.y);
    h.z = fmaf(MUP, y.z, h.z); h.w = fmaf(MUP, y.w, h.w);
    float ssv = h.x*h.x + h.y*h.y + h.z*h.z + h.w*h.w;
    float v = wsum64(ssv);
    if (lane == 0) sred[w] = v;
    __syncthreads();
    float rstd = rsqrtf((sred[0] + sred[1] + sred[2] + sred[3]) * (1.f/1024.f) + EPS);
    float4 g4 = ((const float4*)normw)[tid];
    float4 o;
    o.x = h.x * rstd * g4.x; o.y = h.y * rstd * g4.y;
    o.z = h.z * rstd * g4.z; o.w = h.w * rstd * g4.w;
    ((float4*)out)[b * 256 + tid] = o;
}

extern "C" void kernel_launch(void* const* d_in, const int* in_sizes, int n_in,
                              void* d_out, int out_size, void* d_ws, size_t ws_size,
                              hipStream_t stream) {
    const float* emb  = (const float*)d_in[0];
    const float* kc   = (const float*)d_in[1];
    const float* vc   = (const float*)d_in[2];
    const float* ln1  = (const float*)d_in[3];
    const float* ln2  = (const float*)d_in[4];
    const float* nrmw = (const float*)d_in[5];
    const float* wq   = (const float*)d_in[6];
    const float* wk   = (const float*)d_in[7];
    const float* wv   = (const float*)d_in[8];
    const float* wo   = (const float*)d_in[9];
    const float* wg   = (const float*)d_in[10];
    const float* wu   = (const float*)d_in[11];
    const float* wd   = (const float*)d_in[12];
    const int*   cl   = (const int*)d_in[13];

    float* out = (float*)d_out;
    float* ws  = (float*)d_ws;
    float* nk  = out + OUT_NK;
    float* nv  = out + OUT_NV;

    k_init<<<3, 256, 0, stream>>>(emb, cl, ws, out);
    for (int l = 0; l < 16; ++l) {
        k_a<<<66, 512, 0, stream>>>(ln1, wq, wk, wv, ws, l);
        k_b<<<256, 256, 0, stream>>>(kc, vc, cl, ws, nk, nv, l);
        k_c<<<34, 512, 0, stream>>>(wo, ws, l);
        k_d<<<dim3(16, 8), 512, 0, stream>>>(ln2, wg, wu, ws, l);
        k_e<<<dim3(4, 32), 512, 0, stream>>>(wd, ws, l);
    }
    k_final<<<4, 256, 0, stream>>>(nrmw, ws, out);
}